// Round 12
// baseline (608.819 us; speedup 1.0000x reference)
//
#include <hip/hip_runtime.h>

typedef float    f32x4  __attribute__((ext_vector_type(4)));
typedef float    f32x16 __attribute__((ext_vector_type(16)));
typedef _Float16 f16x4  __attribute__((ext_vector_type(4)));
typedef _Float16 f16x8  __attribute__((ext_vector_type(8)));

#define N_IMG 50000
#define NPAD  50176       // imgh padded rows (zeros beyond 50000)
#define BROWS 256
#define CHW   3072
#define BK    64
#define BM    128
#define BN    128
#define EHS   50176       // padded k stride for eh (zeros beyond 50000)
#define KCHUNK 3136       // 49*64 split-K chunk for GEMM2 (16*3136 = 50176)
#define NSPLIT 16

// direct global->LDS (wave-uniform LDS base + lane*16B; per-lane global addr)
__device__ __forceinline__ void glds16(const void* g, void* l) {
    __builtin_amdgcn_global_load_lds(
        (const __attribute__((address_space(1))) void*)g,
        (__attribute__((address_space(3))) void*)l, 16, 0, 0);
}

// ---------------- scalars from t ----------------
__global__ void k_scalars(const float* __restrict__ t, float* __restrict__ sc) {
    if (threadIdx.x == 0) {
        double tv  = (double)t[0];
        double ang = tv * (1.5707963267948966 / 1.008);
        double c   = cos(ang);
        double at  = c;
        double bt2 = 1.0 - c * c;
        sc[0] = (float)at;
        sc[1] = (float)bt2;
        sc[2] = (float)(at / bt2);             // c_cross
        sc[3] = (float)(at * at * 0.5 / bt2);  // c_y2
        sc[4] = (float)(1.0 / bt2);            // inv_bt2
    }
}

// ---------------- x -> f16 ----------------
// -||x||^2 logit term is a per-row constant -> cancelled by row softmax; omitted.
__global__ void k_xprep(const float* __restrict__ x, _Float16* __restrict__ xh) {
    int idx = blockIdx.x * 256 + threadIdx.x;
    f32x4 v = ((const f32x4*)x)[idx];
    f16x4 h;
    h[0] = (_Float16)v[0]; h[1] = (_Float16)v[1];
    h[2] = (_Float16)v[2]; h[3] = (_Float16)v[3];
    ((f16x4*)xh)[idx] = h;
}

// ---------------- GEMM1' (prep fused): logits = c_cross*(xh@imgT) - c_y2*y2 ----------
// B staged from img f32 (reg->cvt->LDS), y2 folded locally, imgh f16 written as
// side effect (m=0 blocks only; m-pair shares f32 read via same-XCD L2).
// A (xh): glds, double-buffered (Alds 2x16KB). LDS total 48KB -> 3 blk/CU.
// Per iter: P1 = cvt+ds_write B(it) + imgh stores; P2 = prefetch(it+1) + MFMA.
__global__ __launch_bounds__(256, 3) void k_gemm1(
        const _Float16* __restrict__ xh, const float* __restrict__ img,
        _Float16* __restrict__ imgh, const float* __restrict__ sc,
        float* __restrict__ logits) {
    __shared__ _Float16 Alds[2][BM * BK];  // 2 x 16 KB, swizzled granules
    __shared__ _Float16 Blds[BN * BK];     // 16 KB, [row][g^(row&7)] granules
    __shared__ float y2lds[BN];

    const int tid = threadIdx.x;
    const int wid = tid >> 6, lane = tid & 63;
    const int flat = blockIdx.x;          // 0..783
    const int xcd = flat & 7, loc = flat >> 3;          // loc 0..97
    const int m0 = (loc & 1) * BM;
    const int n0 = (xcd * 49 + (loc >> 1)) * BN;

    // A staging (glds)
    const _Float16* gA[4]; int lAo[4];
    #pragma unroll
    for (int j = 0; j < 4; j++) {
        int seg = wid * 4 + j;
        int row = seg * 8 + (lane >> 3);
        int off = (((lane & 7) ^ (row & 7)) << 3);   // f16 elements
        gA[j] = xh + (size_t)(m0 + row) * CHW + off;
        lAo[j] = seg * 512;
    }

    // B staging from f32: thread -> (row br, half bh: k cols bh*32..+31)
    const int br = tid >> 1;              // 0..127
    const int bh = tid & 1;               // 0/1
    const int bn = n0 + br;
    const bool bvalid = bn < N_IMG;
    const bool bwrite = (m0 == 0);        // dedup imgh writes across m-pair
    const float* bsrc = img + (size_t)(bvalid ? bn : 0) * CHW + bh * 32;
    _Float16* ihdst = imgh + (size_t)bn * CHW + bh * 32;
    char* bld = (char*)Blds + br * 128;   // + granule slot << 4

    f32x4 breg[8];
    float y2p = 0.f;
    auto loadB = [&](int kt) {
        #pragma unroll
        for (int i = 0; i < 8; i++) breg[i] = *(const f32x4*)(bsrc + kt + i * 4);
    };

    const int wm = wid >> 1, wn = wid & 1;
    const int rm = wm * 64, cn = wn * 64;
    const int lr = lane & 31, hi = lane >> 5;
    const int xm = (lr & 7) << 4;                    // read-side byte XOR
    const int ar0 = (rm + lr) * 128,      ar1 = (rm + 32 + lr) * 128;
    const int br0 = (cn + lr) * 128,      br1 = (cn + 32 + lr) * 128;
    const int kof = hi * 16;
    const char* Bb = (const char*)Blds;

    f32x16 acc[2][2];
    #pragma unroll
    for (int mi = 0; mi < 2; mi++)
        #pragma unroll
        for (int ni = 0; ni < 2; ni++)
            #pragma unroll
            for (int r = 0; r < 16; r++) acc[mi][ni][r] = 0.f;

    // prologue: stage it=0
    #pragma unroll
    for (int j = 0; j < 4; j++) glds16(gA[j], (_Float16*)Alds[0] + lAo[j]);
    loadB(0);

    int c = 0;
    const f32x4 fz = {0.f, 0.f, 0.f, 0.f};
    for (int it = 0; it < CHW / BK; ++it) {
        __syncthreads();   // glds A(it) + breg(it) landed; prev MFMA Blds reads done

        // P1: cvt + y2 + ds_write B(it) -> Blds; imgh f16 stores
        if (!bvalid) {
            #pragma unroll
            for (int i = 0; i < 8; i++) breg[i] = fz;
        }
        #pragma unroll
        for (int gi = 0; gi < 4; gi++) {
            f32x4 a = breg[2 * gi], b = breg[2 * gi + 1];
            f16x8 h;
            #pragma unroll
            for (int q = 0; q < 4; q++) {
                h[q]     = (_Float16)a[q];
                h[4 + q] = (_Float16)b[q];
                y2p += a[q] * a[q] + b[q] * b[q];
            }
            *(f16x8*)(bld + (((bh * 4 + gi) ^ (br & 7)) << 4)) = h;
            if (bwrite) *(f16x8*)(ihdst + it * BK + gi * 8) = h;
        }
        __syncthreads();   // Blds(it) ready

        // P2: prefetch it+1 (drains at next loop-top barrier) + MFMA
        if (it + 1 < CHW / BK) {
            #pragma unroll
            for (int j = 0; j < 4; j++)
                glds16(gA[j] + (it + 1) * BK, (_Float16*)Alds[c ^ 1] + lAo[j]);
            loadB((it + 1) * BK);
        }
        const char* Ab = (const char*)Alds[c];
        #pragma unroll
        for (int ks = 0; ks < 4; ++ks) {
            int off = (ks * 32 + kof) ^ xm;
            f16x8 a0 = *(const f16x8*)(Ab + ar0 + off);
            f16x8 a1 = *(const f16x8*)(Ab + ar1 + off);
            f16x8 b0 = *(const f16x8*)(Bb + br0 + off);
            f16x8 b1 = *(const f16x8*)(Bb + br1 + off);
            acc[0][0] = __builtin_amdgcn_mfma_f32_32x32x16_f16(a0, b0, acc[0][0], 0, 0, 0);
            acc[0][1] = __builtin_amdgcn_mfma_f32_32x32x16_f16(a0, b1, acc[0][1], 0, 0, 0);
            acc[1][0] = __builtin_amdgcn_mfma_f32_32x32x16_f16(a1, b0, acc[1][0], 0, 0, 0);
            acc[1][1] = __builtin_amdgcn_mfma_f32_32x32x16_f16(a1, b1, acc[1][1], 0, 0, 0);
        }
        c ^= 1;
    }

    // y2 fold: two threads (bh=0/1) per row hold disjoint k partials
    {
        float s = y2p;
        s += __shfl_xor(s, 1);
        if (bh == 0) y2lds[br] = s;
    }
    __syncthreads();

    const float c_cross = sc[2], c_y2 = sc[3];
    #pragma unroll
    for (int mi = 0; mi < 2; mi++)
        #pragma unroll
        for (int ni = 0; ni < 2; ni++) {
            int col = n0 + cn + ni * 32 + lr;
            if (col >= N_IMG) continue;
            float y2v = y2lds[cn + ni * 32 + lr];
            f32x16 v = acc[mi][ni];
            #pragma unroll
            for (int r = 0; r < 16; r++) {
                int row = m0 + rm + mi * 32 + (r & 3) + 8 * (r >> 2) + 4 * hi;
                logits[(size_t)row * N_IMG + col] = c_cross * v[r] - c_y2 * y2v;
            }
        }
}

// ---------------- fused row max + exp + row sum (writes padded eh) ----------------
__global__ void k_softmax(const float* __restrict__ logits, _Float16* __restrict__ eh,
                          float* __restrict__ rowsum) {
    int row = blockIdx.x, tid = threadIdx.x;
    const f32x4* lr = (const f32x4*)(logits + (size_t)row * N_IMG);
    _Float16* erow = eh + (size_t)row * EHS;
    f16x4* er = (f16x4*)erow;
    __shared__ float wred[4];

    if (tid < EHS - N_IMG) erow[N_IMG + tid] = (_Float16)0.f;   // zero K-tail pad

    float m = -3.0e38f;
    for (int i = tid; i < N_IMG / 4; i += 256) {
        f32x4 v = lr[i];
        m = fmaxf(m, fmaxf(fmaxf(v[0], v[1]), fmaxf(v[2], v[3])));
    }
    for (int o = 32; o > 0; o >>= 1) m = fmaxf(m, __shfl_down(m, o));
    if ((tid & 63) == 0) wred[tid >> 6] = m;
    __syncthreads();
    m = fmaxf(fmaxf(wred[0], wred[1]), fmaxf(wred[2], wred[3]));
    __syncthreads();

    float s = 0.f;
    for (int i = tid; i < N_IMG / 4; i += 256) {
        f32x4 v = lr[i];
        float e0 = __expf(v[0] - m), e1 = __expf(v[1] - m);
        float e2 = __expf(v[2] - m), e3 = __expf(v[3] - m);
        s += (e0 + e1) + (e2 + e3);
        f16x4 h;
        h[0] = (_Float16)e0; h[1] = (_Float16)e1;
        h[2] = (_Float16)e2; h[3] = (_Float16)e3;
        er[i] = h;
    }
    for (int o = 32; o > 0; o >>= 1) s += __shfl_down(s, o);
    if ((tid & 63) == 0) wred[tid >> 6] = s;
    __syncthreads();
    if (tid == 0) rowsum[row] = (wred[0] + wred[1]) + (wred[2] + wred[3]);
}

// ---------------- GEMM2: partial[ck] = eh[:,chunk] @ imgh[chunk,:] ----------------
// Fused in-LDS transpose v4 (R10/R11 proven): P1: A-frags->regs + transpose
// Tmp->Blds. P2: glds(it+1) overlapped with MFMA (A from regs, B from Blds).
__global__ __launch_bounds__(256, 3) void k_gemm2(
        const _Float16* __restrict__ eh, const _Float16* __restrict__ imgh,
        float* __restrict__ partial) {
    __shared__ _Float16 Alds[BM * BK];     // 16 KB, swizzled (A = eh)
    __shared__ _Float16 Blds[BN * BK];     // 16 KB, [d][k] swizzled granules
    __shared__ _Float16 Tmp[BK * BN];      // 16 KB, [k][d] linear

    const int tid = threadIdx.x;
    const int wid = tid >> 6, lane = tid & 63;
    const int flat = blockIdx.x;          // 0..767
    const int xcd = flat & 7, loc = flat >> 3;          // loc 0..95
    const int ck  = xcd * 2 + (loc >= 48 ? 1 : 0);
    const int rem = loc - (loc >= 48 ? 48 : 0);         // 0..47
    const int m0 = (rem & 1) * BM;
    const int d0 = (rem >> 1) * BN;
    const int kbase = ck * KCHUNK;

    const _Float16* gA[4]; _Float16* lA[4];
    const _Float16* gB[4]; _Float16* lB[4];
    #pragma unroll
    for (int j = 0; j < 4; j++) {
        int seg = wid * 4 + j;                         // 0..15
        int row = seg * 8 + (lane >> 3);
        int off = (((lane & 7) ^ (row & 7)) << 3);
        gA[j] = eh + (size_t)(m0 + row) * EHS + kbase + off;
        lA[j] = Alds + seg * 512;
        gB[j] = imgh + (size_t)(kbase + seg * 4 + (lane >> 4)) * CHW + d0 + (lane & 15) * 8;
        lB[j] = Tmp + seg * 512;
    }

    const int q   = tid & 31;             // d-quad 0..31
    const int oct = tid >> 5;             // k-octet 0..7

    const int wm = wid >> 1, wn = wid & 1;
    const int rm = wm * 64, cn = wn * 64;
    const int lr = lane & 31, hi = lane >> 5;
    const int xm = (lr & 7) << 4;
    const int ar0 = (rm + lr) * 128, ar1 = (rm + 32 + lr) * 128;
    const int br0 = (cn + lr) * 128, br1 = (cn + 32 + lr) * 128;
    const int kof = hi * 16;
    const char* Ab = (const char*)Alds;
    const char* Bb = (const char*)Blds;

    f32x16 acc[2][2];
    #pragma unroll
    for (int mi = 0; mi < 2; mi++)
        #pragma unroll
        for (int ni = 0; ni < 2; ni++)
            #pragma unroll
            for (int r = 0; r < 16; r++) acc[mi][ni][r] = 0.f;

    #pragma unroll
    for (int j = 0; j < 4; j++) glds16(gA[j], lA[j]);
    #pragma unroll
    for (int j = 0; j < 4; j++) glds16(gB[j], lB[j]);

    f16x8 afr0[4], afr1[4];

    for (int it = 0; it < KCHUNK / BK; ++it) {
        __syncthreads();   // glds(it) drained; MFMA(it-1) Blds reads done

        #pragma unroll
        for (int ks = 0; ks < 4; ++ks) {
            int offa = (ks * 32 + kof) ^ xm;
            afr0[ks] = *(const f16x8*)(Ab + ar0 + offa);
            afr1[ks] = *(const f16x8*)(Ab + ar1 + offa);
        }
        {
            f16x4 r[8];
            #pragma unroll
            for (int j = 0; j < 8; j++)
                r[j] = *(const f16x4*)&Tmp[(oct * 8 + j) * 128 + q * 4];
            #pragma unroll
            for (int dd = 0; dd < 4; dd++) {
                f16x8 w;
                #pragma unroll
                for (int j = 0; j < 8; j++) w[j] = r[j][dd];
                int d = q * 4 + dd;
                *(f16x8*)((char*)Blds + d * 128 + ((oct ^ (d & 7)) << 4)) = w;
            }
        }
        __syncthreads();   // Blds ready; Alds/Tmp free for prefetch

        if (it + 1 < KCHUNK / BK) {
            #pragma unroll
            for (int j = 0; j < 4; j++) glds16(gA[j] + (it + 1) * BK, lA[j]);
            #pragma unroll
            for (int j = 0; j < 4; j++) glds16(gB[j] + (size_t)(it + 1) * BK * CHW, lB[j]);
        }
        #pragma unroll
        for (int ks = 0; ks < 4; ++ks) {
            int offb = (ks * 32 + kof) ^ xm;
            f16x8 b0 = *(const f16x8*)(Bb + br0 + offb);
            f16x8 b1 = *(const f16x8*)(Bb + br1 + offb);
            acc[0][0] = __builtin_amdgcn_mfma_f32_32x32x16_f16(afr0[ks], b0, acc[0][0], 0, 0, 0);
            acc[0][1] = __builtin_amdgcn_mfma_f32_32x32x16_f16(afr0[ks], b1, acc[0][1], 0, 0, 0);
            acc[1][0] = __builtin_amdgcn_mfma_f32_32x32x16_f16(afr1[ks], b0, acc[1][0], 0, 0, 0);
            acc[1][1] = __builtin_amdgcn_mfma_f32_32x32x16_f16(afr1[ks], b1, acc[1][1], 0, 0, 0);
        }
    }

    float* pp = partial + (size_t)ck * BROWS * CHW;
    #pragma unroll
    for (int mi = 0; mi < 2; mi++)
        #pragma unroll
        for (int ni = 0; ni < 2; ni++) {
            int dcol = d0 + cn + ni * 32 + lr;
            f32x16 v = acc[mi][ni];
            #pragma unroll
            for (int r = 0; r < 16; r++) {
                int row = m0 + rm + mi * 32 + (r & 3) + 8 * (r >> 2) + 4 * hi;
                pp[(size_t)row * CHW + dcol] = v[r];
            }
        }
}

// ---------------- reduce partials + final score ----------------
__global__ void k_final(const float* __restrict__ partial, const float* __restrict__ x,
                        const float* __restrict__ rowsum, const float* __restrict__ sc,
                        float* __restrict__ out) {
    int idx = blockIdx.x * 256 + threadIdx.x;
    int row = idx / (CHW / 4);
    float at = sc[0], invbt2 = sc[4];
    float scale = at * invbt2 / rowsum[row];
    const f32x4* p4 = (const f32x4*)partial;
    f32x4 s = p4[idx];
    #pragma unroll
    for (int c = 1; c < NSPLIT; c++) s = s + p4[(size_t)c * (BROWS * CHW / 4) + idx];
    f32x4 xv = ((const f32x4*)x)[idx];
    f32x4 o;
    #pragma unroll
    for (int j = 0; j < 4; j++) o[j] = s[j] * scale - xv[j] * invbt2;
    ((f32x4*)out)[idx] = o;
}

extern "C" void kernel_launch(void* const* d_in, const int* in_sizes, int n_in,
                              void* d_out, int out_size, void* d_ws, size_t ws_size,
                              hipStream_t stream) {
    const float* t   = (const float*)d_in[0];
    const float* x   = (const float*)d_in[1];
    const float* img = (const float*)d_in[2];
    float* out = (float*)d_out;
    char* ws = (char*)d_ws;

    // ws layout (bytes)
    float*    sc     = (float*)(ws + 0);                   // 64 B
    float*    rowsum = (float*)(ws + 256);                 // 1 KB
    _Float16* xh     = (_Float16*)(ws + 212992);           // 1.5 MB
    _Float16* imgh   = (_Float16*)(ws + 2097152);          // 308.3 MB [NPAD][CHW]
    _Float16* eh     = (_Float16*)(ws + 310378496);        // 25.7 MB  [b][EHS]
    float*    logits = (float*)(ws + 336068608);           // 51.2 MB
    float*    partial = logits;                            // reused (50.4 MB)

    k_scalars<<<1, 64, 0, stream>>>(t, sc);
    k_xprep<<<(BROWS * CHW / 4) / 256, 256, 0, stream>>>(x, xh);
    k_gemm1<<<784, 256, 0, stream>>>(xh, img, imgh, sc, logits);
    k_softmax<<<256, 256, 0, stream>>>(logits, eh, rowsum);
    k_gemm2<<<768, 256, 0, stream>>>(eh, imgh, partial);
    k_final<<<(BROWS * CHW / 4) / 256, 256, 0, stream>>>(partial, x, rowsum, sc, out);
}